// Round 3
// baseline (266.439 us; speedup 1.0000x reference)
//
#include <hip/hip_runtime.h>

#define TSC_OUT_LEN 16384
#define TSC_ENC_LEN 16368   // 16384 - 16384/1024
#define TSC_ROWS 16         // rows processed per block

// readfirstlane on a float: forces a block/wave-uniform value into an SGPR.
__device__ __forceinline__ float tsc_rfl(float x) {
    return __uint_as_float(__builtin_amdgcn_readfirstlane(__float_as_uint(x)));
}

// One row's worth of per-thread input coefficients (10 loads for 8 outputs).
struct TscLd {
    float4 d1;                       // e=1 coeffs
    float2 d2;                       // e=2 coeffs
    float  c3;                       // e=3 coeff
    float  c4, c5, c6, c7, c8;       // e=4..8 coeffs
    float  c9, c10;                  // e=9,10 coeffs (wave-uniform)
};

// out[b,j] = sum_{e=1..10} data[b, off_e + (j>>e)] * weights[(2^e-1) + (j&(2^e-1))] + sum_e bias[e-1]
//
// Column-persistent blocks (tile, row-group), weights fully loop-invariant:
// e=1..3 block-uniform -> SGPRs, e=4..10 in 56 VGPRs. Grid = 1024 = 4
// blocks/CU, all resident in one round.
//
// R2 post-mortem: BW pinned at 2.5 TB/s across 3 structures == outstanding-
// bytes limit (Little's law), not duty cycle. Fix: 4-deep row pipeline so
// each wave holds THREE rows' loads (~6 KB) permanently in flight instead of
// one (~2 KB). Buffer rotation is fully static (4x-unrolled body) so the
// TscLd structs stay in registers (runtime indexing would go to scratch).
__global__ __launch_bounds__(256, 4) void tsc_transpose_kernel(
    const float* __restrict__ data,
    const float* __restrict__ weights,
    const float* __restrict__ bias,
    float* __restrict__ out)
{
    __shared__ float wl[2048];
    const int tid = threadIdx.x;
    for (int i = tid; i < 2047; i += 256) wl[i + 1] = weights[i];
    __syncthreads();

    const int tile = blockIdx.x & 7;             // output column tile (0..7)
    const int rg   = blockIdx.x >> 3;            // row group (0..127)
    const int j0   = (tile << 11) + (tid << 3);  // fixed 8-aligned output column

    // Sum of all per-scale biases — one constant added to every output.
    float bs = 0.0f;
#pragma unroll
    for (int i = 0; i < 10; ++i) bs += bias[i];

    // e=1..3 weights: identical for every thread in the block -> SGPRs.
    const float w1a = tsc_rfl(wl[2]), w1b = tsc_rfl(wl[3]);
    const float w2a = tsc_rfl(wl[4]), w2b = tsc_rfl(wl[5]);
    const float w2c = tsc_rfl(wl[6]), w2d = tsc_rfl(wl[7]);
    float w3[8];
#pragma unroll
    for (int i = 0; i < 8; ++i) w3[i] = tsc_rfl(wl[8 + i]);

    // e=4..10 weights: fixed per thread, register-resident (7 x 8 floats).
    float4 wa[7], wb[7];
#pragma unroll
    for (int e = 4; e <= 10; ++e) {
        const int w  = 1 << e;
        const int kb = w + (j0 & (w - 1));   // 8-aligned -> 16B-aligned LDS reads
        wa[e - 4] = *reinterpret_cast<const float4*>(&wl[kb]);
        wb[e - 4] = *reinterpret_cast<const float4*>(&wl[kb + 4]);
    }

    // Loop-invariant per-lane element offsets into a data row.
    const int i1 = (j0 >> 1);                  // float4, 16B aligned
    const int i2 = 8192  + (j0 >> 2);          // float2, 8B aligned
    const int i3 = 12288 + (j0 >> 3);
    const int i4 = 14336 + (j0 >> 4);
    const int i5 = 15360 + (j0 >> 5);
    const int i6 = 15872 + (j0 >> 6);
    const int i7 = 16128 + (j0 >> 7);
    const int i8 = 16256 + (j0 >> 8);
    const int i9  = 16320 + __builtin_amdgcn_readfirstlane(j0 >> 9);
    const int i10 = 16352 + __builtin_amdgcn_readfirstlane(j0 >> 10);

    const float* drow = data + (size_t)rg * TSC_ROWS * TSC_ENC_LEN;
    float*       orow = out  + (size_t)rg * TSC_ROWS * TSC_OUT_LEN + j0;

    auto issue = [&](const float* dp, TscLd& L) {
        L.d1  = *reinterpret_cast<const float4*>(dp + i1);
        L.d2  = *reinterpret_cast<const float2*>(dp + i2);
        L.c3  = dp[i3];
        L.c4  = dp[i4];
        L.c5  = dp[i5];
        L.c6  = dp[i6];
        L.c7  = dp[i7];
        L.c8  = dp[i8];
        L.c9  = dp[i9];
        L.c10 = dp[i10];
    };

    auto compute_store = [&](const TscLd& L, float* op) {
        float a0 = bs, a1 = bs, a2 = bs, a3 = bs;
        float a4 = bs, a5 = bs, a6 = bs, a7 = bs;
        // e = 1
        a0 = fmaf(L.d1.x, w1a, a0); a1 = fmaf(L.d1.x, w1b, a1);
        a2 = fmaf(L.d1.y, w1a, a2); a3 = fmaf(L.d1.y, w1b, a3);
        a4 = fmaf(L.d1.z, w1a, a4); a5 = fmaf(L.d1.z, w1b, a5);
        a6 = fmaf(L.d1.w, w1a, a6); a7 = fmaf(L.d1.w, w1b, a7);
        // e = 2
        a0 = fmaf(L.d2.x, w2a, a0); a1 = fmaf(L.d2.x, w2b, a1);
        a2 = fmaf(L.d2.x, w2c, a2); a3 = fmaf(L.d2.x, w2d, a3);
        a4 = fmaf(L.d2.y, w2a, a4); a5 = fmaf(L.d2.y, w2b, a5);
        a6 = fmaf(L.d2.y, w2c, a6); a7 = fmaf(L.d2.y, w2d, a7);
        // e = 3
        a0 = fmaf(L.c3, w3[0], a0); a1 = fmaf(L.c3, w3[1], a1);
        a2 = fmaf(L.c3, w3[2], a2); a3 = fmaf(L.c3, w3[3], a3);
        a4 = fmaf(L.c3, w3[4], a4); a5 = fmaf(L.c3, w3[5], a5);
        a6 = fmaf(L.c3, w3[6], a6); a7 = fmaf(L.c3, w3[7], a7);
        // e = 4..10
#define TSC_E(c, i) \
        a0 = fmaf(c, wa[i].x, a0); a1 = fmaf(c, wa[i].y, a1); \
        a2 = fmaf(c, wa[i].z, a2); a3 = fmaf(c, wa[i].w, a3); \
        a4 = fmaf(c, wb[i].x, a4); a5 = fmaf(c, wb[i].y, a5); \
        a6 = fmaf(c, wb[i].z, a6); a7 = fmaf(c, wb[i].w, a7);
        TSC_E(L.c4, 0)
        TSC_E(L.c5, 1)
        TSC_E(L.c6, 2)
        TSC_E(L.c7, 3)
        TSC_E(L.c8, 4)
        TSC_E(L.c9, 5)
        TSC_E(L.c10, 6)
#undef TSC_E
        float4* o4 = reinterpret_cast<float4*>(op);
        o4[0] = make_float4(a0, a1, a2, a3);
        o4[1] = make_float4(a4, a5, a6, a7);
    };

    // 4-deep software pipeline over rows: three rows' loads always in flight.
    // Static rotation L0->L1->L2->L3 via 4x-unrolled body; no conditionals in
    // the steady state (main loop covers rows 0..11, epilogue rows 12..15).
    TscLd L0, L1, L2, L3;
    issue(drow + 0 * TSC_ENC_LEN, L0);
    issue(drow + 1 * TSC_ENC_LEN, L1);
    issue(drow + 2 * TSC_ENC_LEN, L2);
#pragma unroll 1
    for (int r = 0; r < TSC_ROWS - 4; r += 4) {
        issue(drow + 3 * TSC_ENC_LEN, L3); compute_store(L0, orow);
        issue(drow + 4 * TSC_ENC_LEN, L0); compute_store(L1, orow + 1 * TSC_OUT_LEN);
        issue(drow + 5 * TSC_ENC_LEN, L1); compute_store(L2, orow + 2 * TSC_OUT_LEN);
        issue(drow + 6 * TSC_ENC_LEN, L2); compute_store(L3, orow + 3 * TSC_OUT_LEN);
        drow += 4 * TSC_ENC_LEN;
        orow += 4 * TSC_OUT_LEN;
    }
    // Epilogue: rows 12..15 — L0=r12, L1=r13, L2=r14 already in flight.
    issue(drow + 3 * TSC_ENC_LEN, L3);
    compute_store(L0, orow);
    compute_store(L1, orow + 1 * TSC_OUT_LEN);
    compute_store(L2, orow + 2 * TSC_OUT_LEN);
    compute_store(L3, orow + 3 * TSC_OUT_LEN);
}

extern "C" void kernel_launch(void* const* d_in, const int* in_sizes, int n_in,
                              void* d_out, int out_size, void* d_ws, size_t ws_size,
                              hipStream_t stream) {
    const float* data    = (const float*)d_in[0];
    const float* weights = (const float*)d_in[1];
    const float* bias    = (const float*)d_in[2];
    float* out = (float*)d_out;

    const int B = in_sizes[0] / TSC_ENC_LEN;   // 2048
    dim3 grid((B / TSC_ROWS) * 8);             // 8 column tiles x 128 row groups = 1024
    dim3 block(256);
    tsc_transpose_kernel<<<grid, block, 0, stream>>>(data, weights, bias, out);
}

// Round 4
// 243.873 us; speedup vs baseline: 1.0925x; 1.0925x over previous
//
#include <hip/hip_runtime.h>

#define TSC_OUT_LEN 16384
#define TSC_ENC_LEN 16368   // 16384 - 16384/1024
#define TSC_ROWS 16         // rows processed per block

// Raw barrier: writer-side lgkmcnt(0) ensures our ds_writes landed; the empty
// asm after s_barrier stops ds_reads hoisting above it. Crucially this does
// NOT drain vmcnt, so global loads for future rows stay in flight across the
// barrier (unlike __syncthreads, which waits vmcnt(0)).
#define TSC_BARRIER() do { \
    asm volatile("s_waitcnt lgkmcnt(0)" ::: "memory"); \
    __builtin_amdgcn_s_barrier(); \
    asm volatile("" ::: "memory"); \
} while (0)

// readfirstlane on a float: forces a block/wave-uniform value into an SGPR.
__device__ __forceinline__ float tsc_rfl(float x) {
    return __uint_as_float(__builtin_amdgcn_readfirstlane(__float_as_uint(x)));
}

// Per-row register loads: only the two chunky ones (e=1 float4, e=2 float2).
struct TscLd {
    float4 d1;
    float2 d2;
};

// out[b,j] = sum_{e=1..10} data[b, off_e + (j>>e)] * weights[(2^e-1) + (j&(2^e-1))] + sum_e bias[e-1]
//
// R3 post-mortem: 4-deep register pipeline spilled to scratch (FETCH/WRITE
// +46%). R2 body restored. New theory: BW is capped by VMEM request COUNT,
// not bytes (avg request 254 B vs copy-kernel 1 KB; BW ratio matches). Fix:
// the e=3..10 coefficients for a (row, tile) are 510 contiguous-per-scale
// floats -> stage them packed into LDS with float4-only loads (threads 0-126
// one float4, thread 127 one float2), double-buffered across rows. Per
// block-row VMEM requests: 32 -> 10, avg size 254 B -> ~820 B. Compute reads
// c3..c10 from LDS (broadcast/stride-1 reads, conflict-free).
// Packed tail layout (floats): e3 [0,256) e4 [256,384) e5 [384,448)
// e6 [448,480) e7 [480,496) e8 [496,504) e9 [504,508) e10 [508,510).
__global__ __launch_bounds__(256, 4) void tsc_transpose_kernel(
    const float* __restrict__ data,
    const float* __restrict__ weights,
    const float* __restrict__ bias,
    float* __restrict__ out)
{
    __shared__ float wl[2048];
    __shared__ __align__(16) float tail[2][512];
    const int tid = threadIdx.x;
    for (int i = tid; i < 2047; i += 256) wl[i + 1] = weights[i];
    __syncthreads();

    const int tile = blockIdx.x & 7;             // output column tile (0..7)
    const int rg   = blockIdx.x >> 3;            // row group (0..127)
    const int j0   = (tile << 11) + (tid << 3);  // fixed 8-aligned output column

    // Sum of all per-scale biases — one constant added to every output.
    float bs = 0.0f;
#pragma unroll
    for (int i = 0; i < 10; ++i) bs += bias[i];

    // e=1..3 weights: identical for every thread in the block -> SGPRs.
    const float w1a = tsc_rfl(wl[2]), w1b = tsc_rfl(wl[3]);
    const float w2a = tsc_rfl(wl[4]), w2b = tsc_rfl(wl[5]);
    const float w2c = tsc_rfl(wl[6]), w2d = tsc_rfl(wl[7]);
    float w3[8];
#pragma unroll
    for (int i = 0; i < 8; ++i) w3[i] = tsc_rfl(wl[8 + i]);

    // e=4..10 weights: fixed per thread (LDS re-reads are fine if the
    // compiler chooses not to keep them resident).
    float4 wa[7], wb[7];
#pragma unroll
    for (int e = 4; e <= 10; ++e) {
        const int w  = 1 << e;
        const int kb = w + (j0 & (w - 1));   // 8-aligned -> 16B-aligned LDS reads
        wa[e - 4] = *reinterpret_cast<const float4*>(&wl[kb]);
        wb[e - 4] = *reinterpret_cast<const float4*>(&wl[kb + 4]);
    }

    // Direct-load offsets (chunky): e=1 float4, e=2 float2.
    const int i1 = (j0 >> 1);                  // 16B aligned
    const int i2 = 8192 + (j0 >> 2);           // 8B aligned

    // Tail LDS read offsets (local coeff index within the tile).
    const int t3  = tid;                // (tid*8)>>3
    const int t4  = 256 + (tid >> 1);
    const int t5  = 384 + (tid >> 2);
    const int t6  = 448 + (tid >> 3);
    const int t7  = 480 + (tid >> 4);
    const int t8  = 496 + (tid >> 5);
    const int t9  = 504 + (tid >> 6);
    const int t10 = 508 + (tid >> 7);

    // Stage mapping (init-time): thread tid<128 owns packed float4 slot tid.
    int sg = 0;    // global element offset within a data row
    if (tid < 128) {
        int e, bslot;
        if      (tid < 64)  { e = 3;  bslot = 0;   }
        else if (tid < 96)  { e = 4;  bslot = 64;  }
        else if (tid < 112) { e = 5;  bslot = 96;  }
        else if (tid < 120) { e = 6;  bslot = 112; }
        else if (tid < 124) { e = 7;  bslot = 120; }
        else if (tid < 126) { e = 8;  bslot = 124; }
        else if (tid < 127) { e = 9;  bslot = 126; }
        else                { e = 10; bslot = 127; }
        const int off_e = TSC_OUT_LEN - (TSC_OUT_LEN >> (e - 1));
        sg = off_e + tile * (2048 >> e) + ((tid - bslot) << 2);
    }

    const float* drow = data + (size_t)rg * TSC_ROWS * TSC_ENC_LEN;
    float*       orow = out  + (size_t)rg * TSC_ROWS * TSC_OUT_LEN + j0;

    auto issue_d = [&](const float* dp, TscLd& L) {
        L.d1 = *reinterpret_cast<const float4*>(dp + i1);
        L.d2 = *reinterpret_cast<const float2*>(dp + i2);
    };
    auto load_stage = [&](const float* dp) -> float4 {
        float4 v = make_float4(0.f, 0.f, 0.f, 0.f);
        if (tid < 127) {
            v = *reinterpret_cast<const float4*>(dp + sg);
        } else if (tid == 127) {
            const float2 h = *reinterpret_cast<const float2*>(dp + sg);
            v.x = h.x; v.y = h.y;
        }
        return v;
    };
    auto write_stage = [&](const float4& v, float* tb) {
        if (tid < 127) {
            *reinterpret_cast<float4*>(tb + (tid << 2)) = v;
        } else if (tid == 127) {
            tb[508] = v.x; tb[509] = v.y;
        }
    };

    auto compute_store = [&](const TscLd& L, const float* tb, float* op) {
        const float c3  = tb[t3];
        const float c4  = tb[t4];
        const float c5  = tb[t5];
        const float c6  = tb[t6];
        const float c7  = tb[t7];
        const float c8  = tb[t8];
        const float c9  = tb[t9];
        const float c10 = tb[t10];
        float a0 = bs, a1 = bs, a2 = bs, a3 = bs;
        float a4 = bs, a5 = bs, a6 = bs, a7 = bs;
        // e = 1
        a0 = fmaf(L.d1.x, w1a, a0); a1 = fmaf(L.d1.x, w1b, a1);
        a2 = fmaf(L.d1.y, w1a, a2); a3 = fmaf(L.d1.y, w1b, a3);
        a4 = fmaf(L.d1.z, w1a, a4); a5 = fmaf(L.d1.z, w1b, a5);
        a6 = fmaf(L.d1.w, w1a, a6); a7 = fmaf(L.d1.w, w1b, a7);
        // e = 2
        a0 = fmaf(L.d2.x, w2a, a0); a1 = fmaf(L.d2.x, w2b, a1);
        a2 = fmaf(L.d2.x, w2c, a2); a3 = fmaf(L.d2.x, w2d, a3);
        a4 = fmaf(L.d2.y, w2a, a4); a5 = fmaf(L.d2.y, w2b, a5);
        a6 = fmaf(L.d2.y, w2c, a6); a7 = fmaf(L.d2.y, w2d, a7);
        // e = 3
        a0 = fmaf(c3, w3[0], a0); a1 = fmaf(c3, w3[1], a1);
        a2 = fmaf(c3, w3[2], a2); a3 = fmaf(c3, w3[3], a3);
        a4 = fmaf(c3, w3[4], a4); a5 = fmaf(c3, w3[5], a5);
        a6 = fmaf(c3, w3[6], a6); a7 = fmaf(c3, w3[7], a7);
        // e = 4..10
#define TSC_E(c, i) \
        a0 = fmaf(c, wa[i].x, a0); a1 = fmaf(c, wa[i].y, a1); \
        a2 = fmaf(c, wa[i].z, a2); a3 = fmaf(c, wa[i].w, a3); \
        a4 = fmaf(c, wb[i].x, a4); a5 = fmaf(c, wb[i].y, a5); \
        a6 = fmaf(c, wb[i].z, a6); a7 = fmaf(c, wb[i].w, a7);
        TSC_E(c4, 0)
        TSC_E(c5, 1)
        TSC_E(c6, 2)
        TSC_E(c7, 3)
        TSC_E(c8, 4)
        TSC_E(c9, 5)
        TSC_E(c10, 6)
#undef TSC_E
        float4* o4 = reinterpret_cast<float4*>(op);
        o4[0] = make_float4(a0, a1, a2, a3);
        o4[1] = make_float4(a4, a5, a6, a7);
    };

    // Pipeline: d-loads + stage-loads run 1-2 rows ahead; stage float4 lands
    // in LDS one barrier before use. One raw barrier per row.
    TscLd L0, L1;
    float4 S0, S1;
    issue_d(drow,               L0);  S0 = load_stage(drow);
    issue_d(drow + TSC_ENC_LEN, L1);  S1 = load_stage(drow + TSC_ENC_LEN);
    write_stage(S0, tail[0]);          // waits (counted) on S0 only
    TSC_BARRIER();                      // tail[0] readable

#pragma unroll 1
    for (int r = 0; r < TSC_ROWS; r += 2) {
        // ---- row r (even): consumes L0 + tail[0]
        write_stage(S1, tail[1]);                       // row r+1 tail
        compute_store(L0, tail[0], orow);
        if (r + 2 < TSC_ROWS) {
            issue_d(drow + 2 * TSC_ENC_LEN, L0);
            S0 = load_stage(drow + 2 * TSC_ENC_LEN);
        }
        TSC_BARRIER();   // tail[1] readable; tail[0] free (all reads done)

        // ---- row r+1 (odd): consumes L1 + tail[1]
        if (r + 2 < TSC_ROWS) write_stage(S0, tail[0]); // row r+2 tail
        compute_store(L1, tail[1], orow + TSC_OUT_LEN);
        if (r + 3 < TSC_ROWS) {
            issue_d(drow + 3 * TSC_ENC_LEN, L1);
            S1 = load_stage(drow + 3 * TSC_ENC_LEN);
        }
        TSC_BARRIER();   // tail[0] readable; tail[1] free

        drow += 2 * TSC_ENC_LEN;
        orow += 2 * TSC_OUT_LEN;
    }
}

extern "C" void kernel_launch(void* const* d_in, const int* in_sizes, int n_in,
                              void* d_out, int out_size, void* d_ws, size_t ws_size,
                              hipStream_t stream) {
    const float* data    = (const float*)d_in[0];
    const float* weights = (const float*)d_in[1];
    const float* bias    = (const float*)d_in[2];
    float* out = (float*)d_out;

    const int B = in_sizes[0] / TSC_ENC_LEN;   // 2048
    dim3 grid((B / TSC_ROWS) * 8);             // 8 column tiles x 128 row groups = 1024
    dim3 block(256);
    tsc_transpose_kernel<<<grid, block, 0, stream>>>(data, weights, bias, out);
}